// Round 5
// baseline (854.085 us; speedup 1.0000x reference)
//
#include <hip/hip_runtime.h>
#include <stdint.h>
#include <stddef.h>

typedef __bf16 bf16_t;
typedef __bf16 bf16x4 __attribute__((ext_vector_type(4)));
typedef __bf16 bf16x8 __attribute__((ext_vector_type(8)));
typedef float floatx4 __attribute__((ext_vector_type(4)));

#define N_ROWS 16384
#define DIM    1024

__device__ inline bf16x8 cvt_f32x8_bf16(const float* __restrict__ p) {
    floatx4 a = *(const floatx4*)p;
    floatx4 b = *(const floatx4*)(p + 4);
    bf16x8 r;
    r[0] = (bf16_t)a[0]; r[1] = (bf16_t)a[1]; r[2] = (bf16_t)a[2]; r[3] = (bf16_t)a[3];
    r[4] = (bf16_t)b[0]; r[5] = (bf16_t)b[1]; r[6] = (bf16_t)b[2]; r[7] = (bf16_t)b[3];
    return r;
}

__device__ inline void gload_lds16(const bf16_t* g, bf16_t* l) {
    __builtin_amdgcn_global_load_lds(
        (const __attribute__((address_space(1))) void*)g,
        (__attribute__((address_space(3))) void*)l,
        16, 0, 0);
}

// ---------------- f32 -> bf16 batched converter ----------------
struct CvtBatch { const float* src[10]; };

__global__ __launch_bounds__(256) void cvt_f32_bf16_kernel(CvtBatch cb, bf16_t* __restrict__ dst, size_t per) {
    const size_t i = ((size_t)blockIdx.x * 256 + threadIdx.x) * 8;
    const float* s = cb.src[blockIdx.z] + i;
    bf16_t* d = dst + (size_t)blockIdx.z * per + i;
    *(bf16x8*)d = cvt_f32x8_bf16(s);
}

struct GemmBatch {
    const bf16_t* A[9];
    const bf16_t* B[9];
    const float*  bias[9];
    void*         C[9];
};

// ---------- 256x256 GEMM, BK=32, 4-deep LDS pipeline (race-free) ----------
// C[m,n] = sum_k A[m,k]*B[n,k] + bias[n]; K=NN=1024; 512 thr = 8 waves
// (2M x 4N); per-wave C = 128x64 = acc[8][4] 16x16 tiles. 32 K-tiles of BK=32.
// LDS: 4 buffers x [A,B] x [half 128 rows] x [128*32] = 131072 B.
// Per tile: STAGE(kt+3 -> buf (kt+3)&3, idle buffer -> NO read/write race),
// vmcnt(12) (= tiles kt+1..kt+3 in flight, so kt landed), barrier,
// 12 unique ds_read_b128, 32 MFMA (setprio-wrapped), barrier.
// Swizzle (64B rows): slot chunk c holds logical chunk c ^ ((row>>1)&3);
// read addr chunk = lg ^ ((lr>>1)&3) -> 8 lanes/16B-slot balanced, 0-conflict
// (residual 2-way at row+8 is free). gload dest stays linear (rule 21).
template<bool CF32, bool RELU>
__global__ __launch_bounds__(512) void gemm256(GemmBatch g, int nbm) {
    // bijective XCD-stripe decode (requires nbm%8==0; grid = nbm*4*nz)
    const int flat = blockIdx.x;
    const int stripe = nbm >> 3;
    const int xcd = flat & 7, slot = flat >> 3;
    const int bm = xcd * stripe + slot % stripe;
    const int rest = slot / stripe;
    const int bn = rest & 3, z = rest >> 2;

    const bf16_t* __restrict__ A = g.A[z];
    const bf16_t* __restrict__ B = g.B[z];

    __shared__ __align__(16) bf16_t lds[4][2][2][128 * 32];  // 131072 B

    const int t = threadIdx.x, lane = t & 63, w = t >> 6;
    const int wm = w >> 2, wn = w & 3;
    const int lr = lane & 15, lg = lane >> 4;
    const int kx = (lg ^ ((lr >> 1) & 3)) * 8;   // swizzled k-chunk (elems)

    const int am0 = bm * 256, bn0 = bn * 256;

    floatx4 acc[8][4] = {};

    // stage all 4 halves of one K-tile: 4 x gload_lds per thread
    const int srow = t >> 2;
    const int scs  = ((t & 3) ^ ((t >> 3) & 3)) * 8;   // pre-swizzled src col
    const int wb_  = w << 9;                           // per-wave LDS base (elems)
    auto STAGE = [&](int bi, int kt) {
        const size_t coff = (size_t)kt * 32 + scs;
        gload_lds16(A + (size_t)(am0 +       srow) * 1024 + coff, &lds[bi][0][0][wb_]);
        gload_lds16(A + (size_t)(am0 + 128 + srow) * 1024 + coff, &lds[bi][0][1][wb_]);
        gload_lds16(B + (size_t)(bn0 +       srow) * 1024 + coff, &lds[bi][1][0][wb_]);
        gload_lds16(B + (size_t)(bn0 + 128 + srow) * 1024 + coff, &lds[bi][1][1][wb_]);
    };

    STAGE(0, 0);
    STAGE(1, 1);
    STAGE(2, 2);

#pragma unroll 1
    for (int kt = 0; kt < 32; ++kt) {
        const int bi = kt & 3;
        if (kt < 29) STAGE((kt + 3) & 3, kt + 3);
        __builtin_amdgcn_sched_barrier(0);
        if (kt < 29)       asm volatile("s_waitcnt vmcnt(12)" ::: "memory");
        else if (kt == 29) asm volatile("s_waitcnt vmcnt(8)"  ::: "memory");
        else if (kt == 30) asm volatile("s_waitcnt vmcnt(4)"  ::: "memory");
        else               asm volatile("s_waitcnt vmcnt(0)"  ::: "memory");
        __builtin_amdgcn_sched_barrier(0);
        __builtin_amdgcn_s_barrier();       // all waves' tile-kt loads landed
        __builtin_amdgcn_sched_barrier(0);

        bf16x8 af[8], bfv[4];
#pragma unroll
        for (int mi = 0; mi < 8; ++mi)
            af[mi] = *(const bf16x8*)&lds[bi][0][wm][(mi * 16 + lr) * 32 + kx];
#pragma unroll
        for (int ni = 0; ni < 4; ++ni)
            bfv[ni] = *(const bf16x8*)&lds[bi][1][wn >> 1]
                        [((wn & 1) * 64 + ni * 16 + lr) * 32 + kx];

        __builtin_amdgcn_s_setprio(1);
#pragma unroll
        for (int mi = 0; mi < 8; ++mi)
#pragma unroll
            for (int ni = 0; ni < 4; ++ni)
                acc[mi][ni] = __builtin_amdgcn_mfma_f32_16x16x32_bf16(
                    af[mi], bfv[ni], acc[mi][ni], 0, 0, 0);
        __builtin_amdgcn_s_setprio(0);

        __builtin_amdgcn_sched_barrier(0);
        __builtin_amdgcn_s_barrier();       // reads of tile kt consumed
        __builtin_amdgcn_sched_barrier(0);
    }

    // epilogue: C/D layout col=lane&15, row=(lane>>4)*4+rr
    const float* bias = g.bias[z];
#pragma unroll
    for (int ni = 0; ni < 4; ++ni) {
        const int gn = bn0 + wn * 64 + ni * 16 + lr;
        const float bj = bias[gn];
#pragma unroll
        for (int mi = 0; mi < 8; ++mi) {
            const int gm0 = am0 + wm * 128 + mi * 16 + lg * 4;
#pragma unroll
            for (int rr = 0; rr < 4; ++rr) {
                float v = acc[mi][ni][rr] + bj;
                if (RELU) v = v > 0.f ? v : 0.f;
                const size_t idx = (size_t)(gm0 + rr) * 1024 + gn;
                if constexpr (CF32) ((float*)g.C[z])[idx] = v;
                else                ((bf16_t*)g.C[z])[idx] = (bf16_t)v;
            }
        }
    }
}

// ---------------- MFMA wave-per-row attention (barrier-free) ----------------
__global__ __launch_bounds__(256) void attn_kernel(const bf16_t* __restrict__ proj,
                                                   size_t sstride,
                                                   bf16_t* __restrict__ avg) {
    __shared__ __align__(16) bf16_t wlds[4][64 * 72];   // 36864 B
    const int t = threadIdx.x, w = t >> 6, lane = t & 63;
    const int n = blockIdx.x * 4 + w;
    const bf16_t* base = proj + (size_t)n * DIM;
    bf16_t* wb = wlds[w];

    const int q4 = lane & 15;
    const int h4 = lane >> 4;

    floatx4 oacc[4] = {};

    for (int a = 0; a < 3; ++a) {
        const bf16_t* rq = base + (size_t)(3 * a)     * sstride;
        const bf16_t* rk = base + (size_t)(3 * a + 1) * sstride;
        const bf16_t* rv = base + (size_t)(3 * a + 2) * sstride;

        bf16x8 qf[4] = {}, kf[4] = {};
        if (h4 < 2) {
            const bf16_t* qb = rq + h4 * 8 * 64 + q4;
            const bf16_t* kb = rk + h4 * 8 * 64 + q4;
#pragma unroll
            for (int i = 0; i < 4; ++i)
#pragma unroll
                for (int u = 0; u < 8; ++u) {
                    qf[i][u] = qb[u * 64 + i * 16];
                    kf[i][u] = kb[u * 64 + i * 16];
                }
        }

        floatx4 S[4][4];
#pragma unroll
        for (int dt = 0; dt < 4; ++dt)
#pragma unroll
            for (int et = 0; et < 4; ++et)
                S[dt][et] = __builtin_amdgcn_mfma_f32_16x16x32_bf16(
                    qf[dt], kf[et], (floatx4){0.f, 0.f, 0.f, 0.f}, 0, 0, 0);

#pragma unroll
        for (int et = 0; et < 4; ++et) {
            float mx = -1e30f;
#pragma unroll
            for (int dt = 0; dt < 4; ++dt)
#pragma unroll
                for (int rr = 0; rr < 4; ++rr) {
                    float v = S[dt][et][rr] * 0.125f;
                    S[dt][et][rr] = v;
                    mx = fmaxf(mx, v);
                }
            mx = fmaxf(mx, __shfl_xor(mx, 16));
            mx = fmaxf(mx, __shfl_xor(mx, 32));
            float sum = 0.f;
#pragma unroll
            for (int dt = 0; dt < 4; ++dt)
#pragma unroll
                for (int rr = 0; rr < 4; ++rr) {
                    float e = __expf(S[dt][et][rr] - mx);
                    S[dt][et][rr] = e;
                    sum += e;
                }
            sum += __shfl_xor(sum, 16);
            sum += __shfl_xor(sum, 32);
            const float inv = 1.f / sum;
#pragma unroll
            for (int dt = 0; dt < 4; ++dt)
#pragma unroll
                for (int rr = 0; rr < 4; ++rr)
                    wb[(16 * dt + h4 * 4 + rr) * 72 + 16 * et + q4] =
                        (bf16_t)(S[dt][et][rr] * inv);
        }

#pragma unroll
        for (int ks = 0; ks < 2; ++ks) {
            bf16x8 vf = *(const bf16x8*)(rv + q4 * 64 + ks * 32 + h4 * 8);
#pragma unroll
            for (int mt = 0; mt < 4; ++mt) {
                bf16x8 wf = *(const bf16x8*)&wb[(16 * mt + q4) * 72 + ks * 32 + h4 * 8];
                oacc[mt] = __builtin_amdgcn_mfma_f32_16x16x32_bf16(wf, vf, oacc[mt], 0, 0, 0);
            }
        }
    }

    bf16_t* out = avg + (size_t)n * DIM;
    const float inv3 = 1.f / 3.f;
#pragma unroll
    for (int mt = 0; mt < 4; ++mt) {
        bf16x4 pk;
#pragma unroll
        for (int rr = 0; rr < 4; ++rr) pk[rr] = (bf16_t)(oacc[mt][rr] * inv3);
        *(bf16x4*)(out + q4 * 64 + 16 * mt + h4 * 4) = pk;
    }
}

extern "C" void kernel_launch(void* const* d_in, const int* in_sizes, int n_in,
                              void* d_out, int out_size, void* d_ws, size_t ws_size,
                              hipStream_t stream) {
    const float* query = (const float*)d_in[0];
    const float* key_  = (const float*)d_in[1];
    const float* value = (const float*)d_in[2];
    const float* Wq1 = (const float*)d_in[3];  const float* bq1 = (const float*)d_in[4];
    const float* Wk1 = (const float*)d_in[5];  const float* bk1 = (const float*)d_in[6];
    const float* Wv1 = (const float*)d_in[7];  const float* bv1 = (const float*)d_in[8];
    const float* Wq2 = (const float*)d_in[9];  const float* bq2 = (const float*)d_in[10];
    const float* Wk2 = (const float*)d_in[11]; const float* bk2 = (const float*)d_in[12];
    const float* Wv2 = (const float*)d_in[13]; const float* bv2 = (const float*)d_in[14];
    const float* Wq3 = (const float*)d_in[15]; const float* bq3 = (const float*)d_in[16];
    const float* Wk3 = (const float*)d_in[17]; const float* bk3 = (const float*)d_in[18];
    const float* Wv3 = (const float*)d_in[19]; const float* bv3 = (const float*)d_in[20];
    const float* Wo  = (const float*)d_in[21]; const float* bo  = (const float*)d_in[22];

    bf16_t* wB   = (bf16_t*)d_ws;
    bf16_t* inB  = wB + (size_t)10 * 1024 * 1024;
    bf16_t* proj = inB + (size_t)3 * N_ROWS * DIM;

    const size_t fixed = ((size_t)10 * 1024 * 1024 + (size_t)3 * N_ROWS * DIM) * sizeof(bf16_t);
    size_t rem = ws_size > fixed ? ws_size - fixed : 0;
    size_t ch = rem / (10 * DIM * sizeof(bf16_t));
    if (ch > N_ROWS) ch = N_ROWS;
    // CH multiple of 2048 -> rows%2048==0 -> nbm(=rows/256)%8==0 for XCD decode
    int CH = (int)((ch / 2048) * 2048);
    if (CH < 2048) CH = 2048;  // requires ws_size >= ~164 MB (held in all runs)
    bf16_t* avgb = proj + (size_t)9 * CH * DIM;
    const size_t sstride = (size_t)CH * DIM;

    CvtBatch cw;
    const float* worder[10] = {Wq1, Wk2, Wv1, Wq2, Wk1, Wv2, Wq3, Wk3, Wv3, Wo};
    for (int i = 0; i < 10; ++i) cw.src[i] = worder[i];
    cvt_f32_bf16_kernel<<<dim3(512, 1, 10), 256, 0, stream>>>(cw, wB, (size_t)1024 * 1024);

    CvtBatch ci;
    ci.src[0] = query; ci.src[1] = key_; ci.src[2] = value;
    for (int i = 3; i < 10; ++i) ci.src[i] = query;
    cvt_f32_bf16_kernel<<<dim3(8192, 1, 3), 256, 0, stream>>>(ci, inB, (size_t)N_ROWS * DIM);

    static const int ain[9] = {0, 2, 1, 2, 1, 0, 1, 0, 2};
    const float* bs[9] = {bq1, bk2, bv1, bq2, bk1, bv2, bq3, bk3, bv3};

    for (int r0 = 0; r0 < N_ROWS; r0 += CH) {
        const int rows = (N_ROWS - r0 < CH) ? (N_ROWS - r0) : CH;
        const int nbm = rows / 256;

        GemmBatch gp;
        for (int i = 0; i < 9; ++i) {
            gp.A[i]    = inB + ((size_t)ain[i] * N_ROWS + r0) * DIM;
            gp.B[i]    = wB + (size_t)i * 1024 * 1024;
            gp.bias[i] = bs[i];
            gp.C[i]    = proj + (size_t)i * sstride;
        }
        gemm256<false, false><<<dim3(nbm * 4 * 9), 512, 0, stream>>>(gp, nbm);

        attn_kernel<<<dim3(rows / 4), 256, 0, stream>>>(proj, sstride, avgb);

        GemmBatch gf;
        gf.A[0] = avgb;
        gf.B[0] = wB + (size_t)9 * 1024 * 1024;
        gf.bias[0] = bo;
        gf.C[0] = (float*)d_out + (size_t)r0 * DIM;
        for (int i = 1; i < 9; ++i) { gf.A[i] = gf.A[0]; gf.B[i] = gf.B[0]; gf.bias[i] = gf.bias[0]; gf.C[i] = gf.C[0]; }
        gemm256<true, true><<<dim3(nbm * 4), 512, 0, stream>>>(gf, nbm);
    }
}

// Round 6
// 820.941 us; speedup vs baseline: 1.0404x; 1.0404x over previous
//
#include <hip/hip_runtime.h>
#include <stdint.h>
#include <stddef.h>

typedef __bf16 bf16_t;
typedef __bf16 bf16x4 __attribute__((ext_vector_type(4)));
typedef __bf16 bf16x8 __attribute__((ext_vector_type(8)));
typedef float floatx4 __attribute__((ext_vector_type(4)));

#define N_ROWS 16384
#define DIM    1024

__device__ inline bf16x8 cvt_f32x8_bf16(const float* __restrict__ p) {
    floatx4 a = *(const floatx4*)p;
    floatx4 b = *(const floatx4*)(p + 4);
    bf16x8 r;
    r[0] = (bf16_t)a[0]; r[1] = (bf16_t)a[1]; r[2] = (bf16_t)a[2]; r[3] = (bf16_t)a[3];
    r[4] = (bf16_t)b[0]; r[5] = (bf16_t)b[1]; r[6] = (bf16_t)b[2]; r[7] = (bf16_t)b[3];
    return r;
}

__device__ inline void gload_lds16(const bf16_t* g, bf16_t* l) {
    __builtin_amdgcn_global_load_lds(
        (const __attribute__((address_space(1))) void*)g,
        (__attribute__((address_space(3))) void*)l,
        16, 0, 0);
}

// ---------------- f32 -> bf16 batched converter ----------------
struct CvtBatch { const float* src[10]; };

__global__ __launch_bounds__(256) void cvt_f32_bf16_kernel(CvtBatch cb, bf16_t* __restrict__ dst, size_t per) {
    const size_t i = ((size_t)blockIdx.x * 256 + threadIdx.x) * 8;
    const float* s = cb.src[blockIdx.z] + i;
    bf16_t* d = dst + (size_t)blockIdx.z * per + i;
    *(bf16x8*)d = cvt_f32x8_bf16(s);
}

struct GemmBatch {
    const bf16_t* A[9];
    const bf16_t* B[9];
    const float*  bias[9];
    void*         C[9];
};

// ---- 256x256 GEMM, BK=32, 4-deep LDS pipeline + 1-tile register lookahead ----
// Per tile kt: STAGE(kt+3 -> idle buf), vmcnt(8) [tile kt+1 landed, kt+2/kt+3
// in flight], lgkmcnt(0) [own reads of tile kt executed -> overwrite of their
// buf after this barrier is race-free], ONE barrier, issue 12 ds_read_b128 of
// tile kt+1 into the spare frag set, 32 MFMA of tile kt from registers (no
// lgkm dependency -> LDS latency hidden under MFMA). Swizzle as r5 (verified
// conflict-free). Named frag sets A/B alternate via macro (static indexing).
template<bool CF32, bool RELU>
__global__ __launch_bounds__(512, 2) void gemm256(GemmBatch g, int nbm) {
    // bijective XCD-stripe decode (requires nbm%8==0; grid = nbm*4*nz)
    const int flat = blockIdx.x;
    const int stripe = nbm >> 3;
    const int xcd = flat & 7, slot = flat >> 3;
    const int bm = xcd * stripe + slot % stripe;
    const int rest = slot / stripe;
    const int bn = rest & 3, z = rest >> 2;

    const bf16_t* __restrict__ A = g.A[z];
    const bf16_t* __restrict__ B = g.B[z];

    __shared__ __align__(16) bf16_t lds[4][2][2][128 * 32];  // 131072 B

    const int t = threadIdx.x, lane = t & 63, w = t >> 6;
    const int wm = w >> 2, wn = w & 3;
    const int lr = lane & 15, lg = lane >> 4;
    const int kx = (lg ^ ((lr >> 1) & 3)) * 8;   // swizzled k-chunk (elems)

    const int am0 = bm * 256, bn0 = bn * 256;

    floatx4 acc[8][4] = {};

    const int srow = t >> 2;
    const int scs  = ((t & 3) ^ ((t >> 3) & 3)) * 8;   // pre-swizzled src col
    const int wb_  = w << 9;                           // per-wave LDS base
    auto STAGE = [&](int bi, int kt) {
        const size_t coff = (size_t)kt * 32 + scs;
        gload_lds16(A + (size_t)(am0 +       srow) * 1024 + coff, &lds[bi][0][0][wb_]);
        gload_lds16(A + (size_t)(am0 + 128 + srow) * 1024 + coff, &lds[bi][0][1][wb_]);
        gload_lds16(B + (size_t)(bn0 +       srow) * 1024 + coff, &lds[bi][1][0][wb_]);
        gload_lds16(B + (size_t)(bn0 + 128 + srow) * 1024 + coff, &lds[bi][1][1][wb_]);
    };

#define LOADF(kt, af, bfv) do {                                                   \
        const int bi_ = (kt) & 3;                                                 \
        _Pragma("unroll")                                                         \
        for (int mi = 0; mi < 8; ++mi)                                            \
            af[mi] = *(const bf16x8*)&lds[bi_][0][wm][(mi * 16 + lr) * 32 + kx];  \
        _Pragma("unroll")                                                         \
        for (int ni = 0; ni < 4; ++ni)                                            \
            bfv[ni] = *(const bf16x8*)&lds[bi_][1][wn >> 1]                       \
                        [((wn & 1) * 64 + ni * 16 + lr) * 32 + kx];               \
    } while (0)

#define MFMA32(af, bfv) do {                                                      \
        __builtin_amdgcn_s_setprio(1);                                            \
        _Pragma("unroll")                                                         \
        for (int mi = 0; mi < 8; ++mi)                                            \
            _Pragma("unroll")                                                     \
            for (int ni = 0; ni < 4; ++ni)                                        \
                acc[mi][ni] = __builtin_amdgcn_mfma_f32_16x16x32_bf16(            \
                    af[mi], bfv[ni], acc[mi][ni], 0, 0, 0);                       \
        __builtin_amdgcn_s_setprio(0);                                            \
    } while (0)

#define BODY(kt, ca, cb, na, nb) do {                                             \
        if ((kt) + 3 < 32) STAGE(((kt) + 3) & 3, (kt) + 3);                       \
        __builtin_amdgcn_sched_barrier(0);                                        \
        if ((kt) < 29)       asm volatile("s_waitcnt vmcnt(8)" ::: "memory");     \
        else if ((kt) == 29) asm volatile("s_waitcnt vmcnt(4)" ::: "memory");     \
        else if ((kt) == 30) asm volatile("s_waitcnt vmcnt(0)" ::: "memory");     \
        asm volatile("s_waitcnt lgkmcnt(0)" ::: "memory");                        \
        __builtin_amdgcn_sched_barrier(0);                                        \
        __builtin_amdgcn_s_barrier();                                             \
        __builtin_amdgcn_sched_barrier(0);                                        \
        if ((kt) + 1 < 32) LOADF((kt) + 1, na, nb);                               \
        __builtin_amdgcn_sched_barrier(0);                                        \
        MFMA32(ca, cb);                                                           \
    } while (0)

    // prologue: stage tiles 0..2; tile0 landed; read its frags
    STAGE(0, 0);
    STAGE(1, 1);
    STAGE(2, 2);
    __builtin_amdgcn_sched_barrier(0);
    asm volatile("s_waitcnt vmcnt(8)" ::: "memory");
    __builtin_amdgcn_sched_barrier(0);
    __builtin_amdgcn_s_barrier();
    __builtin_amdgcn_sched_barrier(0);

    bf16x8 afA[8], bfA[4], afB[8], bfB[4];
    LOADF(0, afA, bfA);

#pragma unroll 1
    for (int kp = 0; kp < 16; ++kp) {
        const int k0 = 2 * kp;
        BODY(k0,     afA, bfA, afB, bfB);
        BODY(k0 + 1, afB, bfB, afA, bfA);
    }
#undef BODY
#undef MFMA32
#undef LOADF

    // epilogue: C/D layout col=lane&15, row=(lane>>4)*4+rr
    const float* bias = g.bias[z];
#pragma unroll
    for (int ni = 0; ni < 4; ++ni) {
        const int gn = bn0 + wn * 64 + ni * 16 + lr;
        const float bj = bias[gn];
#pragma unroll
        for (int mi = 0; mi < 8; ++mi) {
            const int gm0 = am0 + wm * 128 + mi * 16 + lg * 4;
#pragma unroll
            for (int rr = 0; rr < 4; ++rr) {
                float v = acc[mi][ni][rr] + bj;
                if (RELU) v = v > 0.f ? v : 0.f;
                const size_t idx = (size_t)(gm0 + rr) * 1024 + gn;
                if constexpr (CF32) ((float*)g.C[z])[idx] = v;
                else                ((bf16_t*)g.C[z])[idx] = (bf16_t)v;
            }
        }
    }
}

// ---------------- 128x128 2-phase GEMM (final projection: good grid fill) ----
template<bool CF32, bool RELU>
__global__ __launch_bounds__(256) void gemm_bt16(GemmBatch g, int nbm, int nz) {
    const int K = 1024, NN = 1024;
    int bm, bn, z;
    {
        const int flat = blockIdx.x;
        if ((nbm & 7) == 0) {
            const int stripe = nbm >> 3;
            const int xcd = flat & 7;
            const int slot = flat >> 3;
            const int bml = slot % stripe;
            const int rest = slot / stripe;
            bn = rest & 7;
            z  = rest >> 3;
            bm = xcd * stripe + bml;
        } else {
            bn = flat & 7;
            const int r2 = flat >> 3;
            bm = r2 % nbm;
            z  = r2 / nbm;
        }
    }
    const int t = threadIdx.x, lane = t & 63;
    const int w = t >> 6, wm = w & 1, wn = w >> 1;

    __shared__ __align__(16) bf16_t sA[128 * 32];
    __shared__ __align__(16) bf16_t sB[128 * 32];

    const bf16_t* __restrict__ A = g.A[z];
    const bf16_t* __restrict__ B = g.B[z];

    floatx4 acc[4][4] = {};

    const int r  = t >> 2;
    const int ce = (t & 3) * 8;
    const bf16_t* gA = A + (size_t)(bm * 128 + r) * K + ce;
    const bf16_t* gB = B + (size_t)(bn * 128 + r) * K + ce;
    bf16_t* lA = &sA[(w * 64) * 8];
    bf16_t* lB = &sB[(w * 64) * 8];

    const int aoff = (lane & 15) * 32 + (lane >> 4) * 8;

    for (int kt = 0; kt < K / 32; ++kt) {
        __syncthreads();
        gload_lds16(gA,          lA);
        gload_lds16(gA + 64 * K, lA + 2048);
        gload_lds16(gB,          lB);
        gload_lds16(gB + 64 * K, lB + 2048);
        gA += 32; gB += 32;
        __syncthreads();

        bf16x8 af[4], bfr[4];
#pragma unroll
        for (int i = 0; i < 4; ++i)
            af[i] = *(const bf16x8*)&sA[(wm * 64 + i * 16) * 32 + aoff];
#pragma unroll
        for (int j = 0; j < 4; ++j)
            bfr[j] = *(const bf16x8*)&sB[(wn * 64 + j * 16) * 32 + aoff];
#pragma unroll
        for (int i = 0; i < 4; ++i)
#pragma unroll
            for (int j = 0; j < 4; ++j)
                acc[i][j] = __builtin_amdgcn_mfma_f32_16x16x32_bf16(af[i], bfr[j], acc[i][j], 0, 0, 0);
    }

    const int col = lane & 15;
    const int rbase = (lane >> 4) * 4;
    const float* bias = g.bias[z];
#pragma unroll
    for (int j = 0; j < 4; ++j) {
        const int gn = bn * 128 + wn * 64 + j * 16 + col;
        const float bj = bias[gn];
#pragma unroll
        for (int i = 0; i < 4; ++i) {
            const int gm0 = bm * 128 + wm * 64 + i * 16 + rbase;
#pragma unroll
            for (int rr = 0; rr < 4; ++rr) {
                float v = acc[i][j][rr] + bj;
                if (RELU) v = v > 0.f ? v : 0.f;
                const size_t idx = (size_t)(gm0 + rr) * NN + gn;
                if constexpr (CF32) ((float*)g.C[z])[idx] = v;
                else                ((bf16_t*)g.C[z])[idx] = (bf16_t)v;
            }
        }
    }
}

// ---------------- MFMA wave-per-row attention (barrier-free) ----------------
__global__ __launch_bounds__(256) void attn_kernel(const bf16_t* __restrict__ proj,
                                                   size_t sstride,
                                                   bf16_t* __restrict__ avg) {
    __shared__ __align__(16) bf16_t wlds[4][64 * 72];   // 36864 B
    const int t = threadIdx.x, w = t >> 6, lane = t & 63;
    const int n = blockIdx.x * 4 + w;
    const bf16_t* base = proj + (size_t)n * DIM;
    bf16_t* wb = wlds[w];

    const int q4 = lane & 15;
    const int h4 = lane >> 4;

    floatx4 oacc[4] = {};

    for (int a = 0; a < 3; ++a) {
        const bf16_t* rq = base + (size_t)(3 * a)     * sstride;
        const bf16_t* rk = base + (size_t)(3 * a + 1) * sstride;
        const bf16_t* rv = base + (size_t)(3 * a + 2) * sstride;

        bf16x8 qf[4] = {}, kf[4] = {};
        if (h4 < 2) {
            const bf16_t* qb = rq + h4 * 8 * 64 + q4;
            const bf16_t* kb = rk + h4 * 8 * 64 + q4;
#pragma unroll
            for (int i = 0; i < 4; ++i)
#pragma unroll
                for (int u = 0; u < 8; ++u) {
                    qf[i][u] = qb[u * 64 + i * 16];
                    kf[i][u] = kb[u * 64 + i * 16];
                }
        }

        floatx4 S[4][4];
#pragma unroll
        for (int dt = 0; dt < 4; ++dt)
#pragma unroll
            for (int et = 0; et < 4; ++et)
                S[dt][et] = __builtin_amdgcn_mfma_f32_16x16x32_bf16(
                    qf[dt], kf[et], (floatx4){0.f, 0.f, 0.f, 0.f}, 0, 0, 0);

#pragma unroll
        for (int et = 0; et < 4; ++et) {
            float mx = -1e30f;
#pragma unroll
            for (int dt = 0; dt < 4; ++dt)
#pragma unroll
                for (int rr = 0; rr < 4; ++rr) {
                    float v = S[dt][et][rr] * 0.125f;
                    S[dt][et][rr] = v;
                    mx = fmaxf(mx, v);
                }
            mx = fmaxf(mx, __shfl_xor(mx, 16));
            mx = fmaxf(mx, __shfl_xor(mx, 32));
            float sum = 0.f;
#pragma unroll
            for (int dt = 0; dt < 4; ++dt)
#pragma unroll
                for (int rr = 0; rr < 4; ++rr) {
                    float e = __expf(S[dt][et][rr] - mx);
                    S[dt][et][rr] = e;
                    sum += e;
                }
            sum += __shfl_xor(sum, 16);
            sum += __shfl_xor(sum, 32);
            const float inv = 1.f / sum;
#pragma unroll
            for (int dt = 0; dt < 4; ++dt)
#pragma unroll
                for (int rr = 0; rr < 4; ++rr)
                    wb[(16 * dt + h4 * 4 + rr) * 72 + 16 * et + q4] =
                        (bf16_t)(S[dt][et][rr] * inv);
        }

#pragma unroll
        for (int ks = 0; ks < 2; ++ks) {
            bf16x8 vf = *(const bf16x8*)(rv + q4 * 64 + ks * 32 + h4 * 8);
#pragma unroll
            for (int mt = 0; mt < 4; ++mt) {
                bf16x8 wf = *(const bf16x8*)&wb[(16 * mt + q4) * 72 + ks * 32 + h4 * 8];
                oacc[mt] = __builtin_amdgcn_mfma_f32_16x16x32_bf16(wf, vf, oacc[mt], 0, 0, 0);
            }
        }
    }

    bf16_t* out = avg + (size_t)n * DIM;
    const float inv3 = 1.f / 3.f;
#pragma unroll
    for (int mt = 0; mt < 4; ++mt) {
        bf16x4 pk;
#pragma unroll
        for (int rr = 0; rr < 4; ++rr) pk[rr] = (bf16_t)(oacc[mt][rr] * inv3);
        *(bf16x4*)(out + q4 * 64 + 16 * mt + h4 * 4) = pk;
    }
}

extern "C" void kernel_launch(void* const* d_in, const int* in_sizes, int n_in,
                              void* d_out, int out_size, void* d_ws, size_t ws_size,
                              hipStream_t stream) {
    const float* query = (const float*)d_in[0];
    const float* key_  = (const float*)d_in[1];
    const float* value = (const float*)d_in[2];
    const float* Wq1 = (const float*)d_in[3];  const float* bq1 = (const float*)d_in[4];
    const float* Wk1 = (const float*)d_in[5];  const float* bk1 = (const float*)d_in[6];
    const float* Wv1 = (const float*)d_in[7];  const float* bv1 = (const float*)d_in[8];
    const float* Wq2 = (const float*)d_in[9];  const float* bq2 = (const float*)d_in[10];
    const float* Wk2 = (const float*)d_in[11]; const float* bk2 = (const float*)d_in[12];
    const float* Wv2 = (const float*)d_in[13]; const float* bv2 = (const float*)d_in[14];
    const float* Wq3 = (const float*)d_in[15]; const float* bq3 = (const float*)d_in[16];
    const float* Wk3 = (const float*)d_in[17]; const float* bk3 = (const float*)d_in[18];
    const float* Wv3 = (const float*)d_in[19]; const float* bv3 = (const float*)d_in[20];
    const float* Wo  = (const float*)d_in[21]; const float* bo  = (const float*)d_in[22];

    bf16_t* wB   = (bf16_t*)d_ws;
    bf16_t* inB  = wB + (size_t)10 * 1024 * 1024;
    bf16_t* proj = inB + (size_t)3 * N_ROWS * DIM;

    const size_t fixed = ((size_t)10 * 1024 * 1024 + (size_t)3 * N_ROWS * DIM) * sizeof(bf16_t);
    size_t rem = ws_size > fixed ? ws_size - fixed : 0;
    size_t ch = rem / (10 * DIM * sizeof(bf16_t));
    if (ch > N_ROWS) ch = N_ROWS;
    // CH multiple of 2048 -> nbm256%8==0 and nbm128%8==0 for XCD decode
    int CH = (int)((ch / 2048) * 2048);
    if (CH < 2048) CH = 2048;  // requires ws_size >= ~164 MB (held in all runs)
    bf16_t* avgb = proj + (size_t)9 * CH * DIM;
    const size_t sstride = (size_t)CH * DIM;

    CvtBatch cw;
    const float* worder[10] = {Wq1, Wk2, Wv1, Wq2, Wk1, Wv2, Wq3, Wk3, Wv3, Wo};
    for (int i = 0; i < 10; ++i) cw.src[i] = worder[i];
    cvt_f32_bf16_kernel<<<dim3(512, 1, 10), 256, 0, stream>>>(cw, wB, (size_t)1024 * 1024);

    CvtBatch ci;
    ci.src[0] = query; ci.src[1] = key_; ci.src[2] = value;
    for (int i = 3; i < 10; ++i) ci.src[i] = query;
    cvt_f32_bf16_kernel<<<dim3(8192, 1, 3), 256, 0, stream>>>(ci, inB, (size_t)N_ROWS * DIM);

    static const int ain[9] = {0, 2, 1, 2, 1, 0, 1, 0, 2};
    const float* bs[9] = {bq1, bk2, bv1, bq2, bk1, bv2, bq3, bk3, bv3};

    for (int r0 = 0; r0 < N_ROWS; r0 += CH) {
        const int rows = (N_ROWS - r0 < CH) ? (N_ROWS - r0) : CH;
        const int nbm256 = rows / 256;
        const int nbm128 = rows / 128;

        GemmBatch gp;
        for (int i = 0; i < 9; ++i) {
            gp.A[i]    = inB + ((size_t)ain[i] * N_ROWS + r0) * DIM;
            gp.B[i]    = wB + (size_t)i * 1024 * 1024;
            gp.bias[i] = bs[i];
            gp.C[i]    = proj + (size_t)i * sstride;
        }
        gemm256<false, false><<<dim3(nbm256 * 4 * 9), 512, 0, stream>>>(gp, nbm256);

        attn_kernel<<<dim3(rows / 4), 256, 0, stream>>>(proj, sstride, avgb);

        GemmBatch gf;
        gf.A[0] = avgb;
        gf.B[0] = wB + (size_t)9 * 1024 * 1024;
        gf.bias[0] = bo;
        gf.C[0] = (float*)d_out + (size_t)r0 * DIM;
        for (int i = 1; i < 9; ++i) { gf.A[i] = gf.A[0]; gf.B[i] = gf.B[0]; gf.bias[i] = gf.bias[0]; gf.C[i] = gf.C[0]; }
        gemm_bt16<true, true><<<dim3(nbm128 * 8), 256, 0, stream>>>(gf, nbm128, 1);
    }
}